// Round 3
// baseline (539.981 us; speedup 1.0000x reference)
//
#include <hip/hip_runtime.h>
#include <stdint.h>

typedef __bf16 bf16_t;
typedef __attribute__((ext_vector_type(8))) __bf16 bf16x8;
typedef __attribute__((ext_vector_type(16))) float f32x16;
typedef __attribute__((ext_vector_type(8))) unsigned short ushort8;
typedef __attribute__((ext_vector_type(4))) int int4v;
typedef __attribute__((ext_vector_type(4))) float float4v;

typedef const void __attribute__((address_space(1)))* gptr_t;
typedef void __attribute__((address_space(3)))* lptr_t;

__constant__ float NF4_CB[16] = {
    -1.0f, -0.6961928009986877f, -0.5250730514526367f, -0.39491748809814453f,
    -0.28444138169288635f, -0.18477343022823334f, -0.09105003625154495f, 0.0f,
    0.07958029955625534f, 0.16093020141124725f, 0.24611230194568634f,
    0.33791524171829224f, 0.44070982933044434f, 0.5626170039176941f,
    0.6848514676094055f, 1.0f};

__device__ __forceinline__ unsigned short f32_to_bf16_rne(float f) {
    unsigned int u = __float_as_uint(f);
    u += 0x7FFFu + ((u >> 16) & 1u);
    return (unsigned short)(u >> 16);
}

// Fused preprocessing: W-dequant, X-convert, bias-dequant in one launch.
__global__ void prep_kernel(const int* __restrict__ w_codes,
                            const float* __restrict__ w_absmax,
                            const float* __restrict__ x,
                            const int* __restrict__ b_codes,
                            const float* __restrict__ b_absmax,
                            unsigned short* __restrict__ outW,
                            unsigned short* __restrict__ outA,
                            float* __restrict__ outBias,
                            long w8, long x8, int nbias, long wb, long xb) {
    long blk = blockIdx.x;
    if (blk < wb) {
        long t = blk * blockDim.x + threadIdx.x;
        if (t >= w8) return;
        long base = t * 8;
        float am = w_absmax[t >> 3];
        int4v c0 = *(const int4v*)(w_codes + base);
        int4v c1 = *(const int4v*)(w_codes + base + 4);
        ushort8 v;
        v[0] = f32_to_bf16_rne(NF4_CB[c0[0]] * am);
        v[1] = f32_to_bf16_rne(NF4_CB[c0[1]] * am);
        v[2] = f32_to_bf16_rne(NF4_CB[c0[2]] * am);
        v[3] = f32_to_bf16_rne(NF4_CB[c0[3]] * am);
        v[4] = f32_to_bf16_rne(NF4_CB[c1[0]] * am);
        v[5] = f32_to_bf16_rne(NF4_CB[c1[1]] * am);
        v[6] = f32_to_bf16_rne(NF4_CB[c1[2]] * am);
        v[7] = f32_to_bf16_rne(NF4_CB[c1[3]] * am);
        *(ushort8*)(outW + base) = v;
    } else if (blk < wb + xb) {
        long t = (blk - wb) * blockDim.x + threadIdx.x;
        if (t >= x8) return;
        long base = t * 8;
        float4v f0 = *(const float4v*)(x + base);
        float4v f1 = *(const float4v*)(x + base + 4);
        ushort8 v;
        v[0] = f32_to_bf16_rne(f0[0]);
        v[1] = f32_to_bf16_rne(f0[1]);
        v[2] = f32_to_bf16_rne(f0[2]);
        v[3] = f32_to_bf16_rne(f0[3]);
        v[4] = f32_to_bf16_rne(f1[0]);
        v[5] = f32_to_bf16_rne(f1[1]);
        v[6] = f32_to_bf16_rne(f1[2]);
        v[7] = f32_to_bf16_rne(f1[3]);
        *(ushort8*)(outA + base) = v;
    } else {
        int o = (int)(blk - wb - xb) * blockDim.x + threadIdx.x;
        if (o >= nbias) return;
        outBias[o] = NF4_CB[b_codes[o]] * b_absmax[o >> 6];
    }
}

// C[m][n] = sum_k A[m][k]*B[n][k] + bias[n].
// 128x128 tile, BK=64, XOR-swizzled LDS (0 bank conflicts, verified R2),
// glds width=16 staging, 4 waves in 2x2, each 64x64 via 2x2 of 32x32x16 MFMA
// (4060 FLOP/cyc shape vs 3380 for 16x16x32).
//
// LDS: row r (0..127), k-chunk j (0..7, 16B) at region + r*128B + (j^(r&7))*16B.
// Staging chunk ci (1KB = 8 rows): lane i writes LDS ci*1024 + i*16 =
// row ci*8+(i>>3), slot i&7 -> holds global k-chunk (i&7)^(i>>3).
__global__ void gemm_bias_kernel(const bf16_t* __restrict__ A,
                                 const bf16_t* __restrict__ B,
                                 const float* __restrict__ bias,
                                 float* __restrict__ C,
                                 int M, int N, int K) {
    __shared__ __align__(16) bf16_t sAB[16384];   // 32 KB: A [0,8192), B [8192,16384)

    const int t = threadIdx.x;
    const int lane = t & 63;
    const int wave = t >> 6;
    const int tileM = blockIdx.y * 128;
    const int tileN = blockIdx.x * 128;

    // ---- staging setup (identical to R2) ----
    const int rloc = lane >> 3;
    const int jsw  = (lane & 7) ^ rloc;
    const int chunk0 = wave * 8;
    const int isB = chunk0 >> 4;
    const int ci0 = chunk0 & 15;
    const int r0 = ci0 * 8 + rloc;
    const bf16_t* srcp = (isB ? (B + (size_t)(tileN + r0) * K)
                              : (A + (size_t)(tileM + r0) * K)) + jsw * 8;
    bf16_t* dstp = &sAB[isB * 8192 + ci0 * 512 + lane * 8];
    const size_t srcChunkStride = (size_t)8 * K;

    // ---- fragment read setup (32x32x16: A[m=lane&31][k=(lane>>5)*8+j]) ----
    const int wm = wave >> 1;
    const int wn = wave & 1;
    const int l31 = lane & 31;
    const int kc  = lane >> 5;                   // which 8-elem half of K=16
    const int r7  = l31 & 7;                     // (row&7) — mi*32 doesn't change it
    // element offsets into sAB; all loop-invariant (8 A + 8 B addresses total)
    int aoffs[2][4], boffs[2][4];
#pragma unroll
    for (int mi = 0; mi < 2; ++mi)
#pragma unroll
        for (int s = 0; s < 4; ++s) {
            int jj = ((s * 2 + kc) ^ r7) * 8;
            aoffs[mi][s] = (wm * 64 + mi * 32 + l31) * 64 + jj;
            boffs[mi][s] = 8192 + (wn * 64 + mi * 32 + l31) * 64 + jj;
        }

    f32x16 acc[2][2] = {};

    for (int kt = 0; kt < K; kt += 64) {
#pragma unroll
        for (int j8 = 0; j8 < 8; ++j8)
            __builtin_amdgcn_global_load_lds((gptr_t)(srcp + j8 * srcChunkStride),
                                             (lptr_t)(dstp + j8 * 512), 16, 0, 0);
        srcp += 64;
        __syncthreads();

#pragma unroll
        for (int s = 0; s < 4; ++s) {            // 4 k-steps of 16
            bf16x8 a0 = *(const bf16x8*)&sAB[aoffs[0][s]];
            bf16x8 a1 = *(const bf16x8*)&sAB[aoffs[1][s]];
            bf16x8 b0 = *(const bf16x8*)&sAB[boffs[0][s]];
            bf16x8 b1 = *(const bf16x8*)&sAB[boffs[1][s]];
            acc[0][0] = __builtin_amdgcn_mfma_f32_32x32x16_bf16(a0, b0, acc[0][0], 0, 0, 0);
            acc[0][1] = __builtin_amdgcn_mfma_f32_32x32x16_bf16(a0, b1, acc[0][1], 0, 0, 0);
            acc[1][0] = __builtin_amdgcn_mfma_f32_32x32x16_bf16(a1, b0, acc[1][0], 0, 0, 0);
            acc[1][1] = __builtin_amdgcn_mfma_f32_32x32x16_bf16(a1, b1, acc[1][1], 0, 0, 0);
        }
        __syncthreads();
    }

    // C/D 32x32 layout: col = lane&31, row = (reg&3) + 8*(reg>>2) + 4*(lane>>5).
    const int col0 = tileN + wn * 64 + l31;
    const int rbase = tileM + wm * 64 + 4 * kc;
    float bv[2] = {bias[col0], bias[col0 + 32]};
#pragma unroll
    for (int mi = 0; mi < 2; ++mi)
#pragma unroll
        for (int ni = 0; ni < 2; ++ni)
#pragma unroll
            for (int g = 0; g < 4; ++g)
#pragma unroll
                for (int rr = 0; rr < 4; ++rr) {
                    int row = rbase + mi * 32 + g * 8 + rr;
                    C[(size_t)row * N + (col0 + ni * 32)] =
                        acc[mi][ni][g * 4 + rr] + bv[ni];
                }
}

extern "C" void kernel_launch(void* const* d_in, const int* in_sizes, int n_in,
                              void* d_out, int out_size, void* d_ws, size_t ws_size,
                              hipStream_t stream) {
    const float* x        = (const float*)d_in[0];
    const int*   w_codes  = (const int*)d_in[1];
    const float* w_absmax = (const float*)d_in[2];
    const int*   b_codes  = (const int*)d_in[3];
    const float* b_absmax = (const float*)d_in[4];
    float* out = (float*)d_out;

    const int  D_OUT = in_sizes[3];
    const long WK    = (long)in_sizes[1];
    const int  D_IN  = (int)(WK / D_OUT);
    const long xN    = (long)in_sizes[0];
    const int  M     = (int)(xN / D_IN);
    const int  N = D_OUT, K = D_IN;

    unsigned short* wsW = (unsigned short*)d_ws;
    unsigned short* wsA = wsW + (size_t)N * K;
    float* wsBias = (float*)(wsA + (size_t)M * K);

    long w8 = WK / 8;
    long x8 = xN / 8;
    long wb = (w8 + 255) / 256;
    long xb = (x8 + 255) / 256;
    long bb = (D_OUT + 255) / 256;
    prep_kernel<<<dim3((unsigned)(wb + xb + bb)), dim3(256), 0, stream>>>(
        w_codes, w_absmax, x, b_codes, b_absmax, wsW, wsA, wsBias,
        w8, x8, D_OUT, wb, xb);

    gemm_bias_kernel<<<dim3(N / 128, M / 128), dim3(256), 0, stream>>>(
        (const bf16_t*)wsA, (const bf16_t*)wsW, wsBias, out, M, N, K);
}

// Round 4
// 492.261 us; speedup vs baseline: 1.0969x; 1.0969x over previous
//
#include <hip/hip_runtime.h>
#include <stdint.h>

typedef __bf16 bf16_t;
typedef __attribute__((ext_vector_type(8))) __bf16 bf16x8;
typedef __attribute__((ext_vector_type(4))) float f32x4;
typedef __attribute__((ext_vector_type(8))) unsigned short ushort8;
typedef __attribute__((ext_vector_type(4))) int int4v;
typedef __attribute__((ext_vector_type(4))) float float4v;

typedef const void __attribute__((address_space(1)))* gptr_t;
typedef void __attribute__((address_space(3)))* lptr_t;

__constant__ float NF4_CB[16] = {
    -1.0f, -0.6961928009986877f, -0.5250730514526367f, -0.39491748809814453f,
    -0.28444138169288635f, -0.18477343022823334f, -0.09105003625154495f, 0.0f,
    0.07958029955625534f, 0.16093020141124725f, 0.24611230194568634f,
    0.33791524171829224f, 0.44070982933044434f, 0.5626170039176941f,
    0.6848514676094055f, 1.0f};

__device__ __forceinline__ unsigned short f32_to_bf16_rne(float f) {
    unsigned int u = __float_as_uint(f);
    u += 0x7FFFu + ((u >> 16) & 1u);
    return (unsigned short)(u >> 16);
}

// Fused preprocessing. LDS codebook (avoids per-lane constant-mem gathers),
// 16 elements/thread. Block ranges: [0,wb)->W, [wb,wb+xb)->X, rest->bias.
__global__ void prep_kernel(const int* __restrict__ w_codes,
                            const float* __restrict__ w_absmax,
                            const float* __restrict__ x,
                            const int* __restrict__ b_codes,
                            const float* __restrict__ b_absmax,
                            unsigned short* __restrict__ outW,
                            unsigned short* __restrict__ outA,
                            float* __restrict__ outBias,
                            long w16, long x16, int nbias, long wb, long xb) {
    __shared__ float cb[16];
    if (threadIdx.x < 16) cb[threadIdx.x] = NF4_CB[threadIdx.x];
    __syncthreads();

    long blk = blockIdx.x;
    if (blk < wb) {
        long t = blk * blockDim.x + threadIdx.x;
        if (t >= w16) return;
        long base = t * 16;
        float am = w_absmax[t >> 2];        // 16 codes share one 64-block absmax
        int4v c0 = *(const int4v*)(w_codes + base);
        int4v c1 = *(const int4v*)(w_codes + base + 4);
        int4v c2 = *(const int4v*)(w_codes + base + 8);
        int4v c3 = *(const int4v*)(w_codes + base + 12);
        ushort8 v0, v1;
        v0[0] = f32_to_bf16_rne(cb[c0[0]] * am);
        v0[1] = f32_to_bf16_rne(cb[c0[1]] * am);
        v0[2] = f32_to_bf16_rne(cb[c0[2]] * am);
        v0[3] = f32_to_bf16_rne(cb[c0[3]] * am);
        v0[4] = f32_to_bf16_rne(cb[c1[0]] * am);
        v0[5] = f32_to_bf16_rne(cb[c1[1]] * am);
        v0[6] = f32_to_bf16_rne(cb[c1[2]] * am);
        v0[7] = f32_to_bf16_rne(cb[c1[3]] * am);
        v1[0] = f32_to_bf16_rne(cb[c2[0]] * am);
        v1[1] = f32_to_bf16_rne(cb[c2[1]] * am);
        v1[2] = f32_to_bf16_rne(cb[c2[2]] * am);
        v1[3] = f32_to_bf16_rne(cb[c2[3]] * am);
        v1[4] = f32_to_bf16_rne(cb[c3[0]] * am);
        v1[5] = f32_to_bf16_rne(cb[c3[1]] * am);
        v1[6] = f32_to_bf16_rne(cb[c3[2]] * am);
        v1[7] = f32_to_bf16_rne(cb[c3[3]] * am);
        *(ushort8*)(outW + base) = v0;
        *(ushort8*)(outW + base + 8) = v1;
    } else if (blk < wb + xb) {
        long t = (blk - wb) * blockDim.x + threadIdx.x;
        if (t >= x16) return;
        long base = t * 16;
        float4v f0 = *(const float4v*)(x + base);
        float4v f1 = *(const float4v*)(x + base + 4);
        float4v f2 = *(const float4v*)(x + base + 8);
        float4v f3 = *(const float4v*)(x + base + 12);
        ushort8 v0, v1;
        v0[0] = f32_to_bf16_rne(f0[0]);
        v0[1] = f32_to_bf16_rne(f0[1]);
        v0[2] = f32_to_bf16_rne(f0[2]);
        v0[3] = f32_to_bf16_rne(f0[3]);
        v0[4] = f32_to_bf16_rne(f1[0]);
        v0[5] = f32_to_bf16_rne(f1[1]);
        v0[6] = f32_to_bf16_rne(f1[2]);
        v0[7] = f32_to_bf16_rne(f1[3]);
        v1[0] = f32_to_bf16_rne(f2[0]);
        v1[1] = f32_to_bf16_rne(f2[1]);
        v1[2] = f32_to_bf16_rne(f2[2]);
        v1[3] = f32_to_bf16_rne(f2[3]);
        v1[4] = f32_to_bf16_rne(f3[0]);
        v1[5] = f32_to_bf16_rne(f3[1]);
        v1[6] = f32_to_bf16_rne(f3[2]);
        v1[7] = f32_to_bf16_rne(f3[3]);
        *(ushort8*)(outA + base) = v0;
        *(ushort8*)(outA + base + 8) = v1;
    } else {
        int o = (int)(blk - wb - xb) * blockDim.x + threadIdx.x;
        if (o >= nbias) return;
        outBias[o] = cb[b_codes[o]] * b_absmax[o >> 6];
    }
}

// 256x128 tile, BK=64, 512 threads (8 waves, 4x2 of 64x64), 16x16x32 MFMA
// (R2-verified shape; 32x32x16 regressed with unexplained LDS conflicts — R3).
// XOR-swizzled LDS, glds width=16 staging.
// LDS: A region [0,16384) elems (256 rows x 64), B [16384,24576) (128 rows).
// Row r, k-chunk j (16B) at region + r*128B + (j^(r&7))*16B.
// 48 staging chunks of 1KB (A: 0..31, B: 32..47); wave w owns chunks w*6..w*6+5.
__global__ __launch_bounds__(512) void gemm_bias_kernel_256(
        const bf16_t* __restrict__ A, const bf16_t* __restrict__ B,
        const float* __restrict__ bias, float* __restrict__ C,
        int M, int N, int K) {
    __shared__ __align__(16) bf16_t sAB[24576];   // 48 KB

    const int t = threadIdx.x;
    const int lane = t & 63;
    const int wave = t >> 6;                      // 0..7
    const int tileM = blockIdx.y * 256;
    const int tileN = blockIdx.x * 128;

    const int rloc = lane >> 3;
    const int jsw  = (lane & 7) ^ rloc;
    const bf16_t* srcp[6];
    bf16_t* dstp[6];
#pragma unroll
    for (int j = 0; j < 6; ++j) {
        int c = wave * 6 + j;
        int isB = (c >= 32);
        int r = (isB ? (c - 32) : c) * 8 + rloc;
        const bf16_t* base = isB ? (B + (size_t)(tileN + r) * K)
                                 : (A + (size_t)(tileM + r) * K);
        srcp[j] = base + jsw * 8;
        dstp[j] = &sAB[c * 512 + lane * 8];
    }

    const int wm = wave >> 1;                    // 0..3
    const int wn = wave & 1;
    const int la = lane & 15;
    const int jA = lane >> 4;
    const int jj0 = (jA ^ (lane & 7)) * 8;
    const int aoff = (wm * 64 + la) * 64 + jj0;
    const int boff = 16384 + (wn * 64 + la) * 64 + jj0;

    f32x4 acc[4][4] = {};

    for (int kt = 0; kt < K; kt += 64) {
#pragma unroll
        for (int j = 0; j < 6; ++j) {
            __builtin_amdgcn_global_load_lds((gptr_t)(srcp[j]), (lptr_t)(dstp[j]),
                                             16, 0, 0);
            srcp[j] += 64;
        }
        __syncthreads();

#pragma unroll
        for (int kh = 0; kh < 2; ++kh) {
            const int kx = kh * 32;
            bf16x8 a[4], b[4];
#pragma unroll
            for (int i = 0; i < 4; ++i) a[i] = *(const bf16x8*)&sAB[(aoff + i * 1024) ^ kx];
#pragma unroll
            for (int i = 0; i < 4; ++i) b[i] = *(const bf16x8*)&sAB[(boff + i * 1024) ^ kx];
#pragma unroll
            for (int mi = 0; mi < 4; ++mi)
#pragma unroll
                for (int ni = 0; ni < 4; ++ni)
                    acc[mi][ni] = __builtin_amdgcn_mfma_f32_16x16x32_bf16(
                        a[mi], b[ni], acc[mi][ni], 0, 0, 0);
        }
        __syncthreads();
    }

    const int col0 = tileN + wn * 64 + la;
    const int row0 = tileM + wm * 64 + jA * 4;
    float bv[4];
#pragma unroll
    for (int ni = 0; ni < 4; ++ni) bv[ni] = bias[col0 + ni * 16];
#pragma unroll
    for (int mi = 0; mi < 4; ++mi)
#pragma unroll
        for (int ni = 0; ni < 4; ++ni)
#pragma unroll
            for (int r = 0; r < 4; ++r)
                C[(size_t)(row0 + mi * 16 + r) * N + (col0 + ni * 16)] =
                    acc[mi][ni][r] + bv[ni];
}

// R2 fallback: 128x128 tile, 256 threads (used only if M % 256 != 0).
__global__ void gemm_bias_kernel_128(const bf16_t* __restrict__ A,
                                     const bf16_t* __restrict__ B,
                                     const float* __restrict__ bias,
                                     float* __restrict__ C,
                                     int M, int N, int K) {
    __shared__ __align__(16) bf16_t sAB[16384];
    const int t = threadIdx.x;
    const int lane = t & 63;
    const int wave = t >> 6;
    const int tileM = blockIdx.y * 128;
    const int tileN = blockIdx.x * 128;

    const int rloc = lane >> 3;
    const int jsw  = (lane & 7) ^ rloc;
    const int chunk0 = wave * 8;
    const int isB = chunk0 >> 4;
    const int ci0 = chunk0 & 15;
    const int r0 = ci0 * 8 + rloc;
    const bf16_t* srcp = (isB ? (B + (size_t)(tileN + r0) * K)
                              : (A + (size_t)(tileM + r0) * K)) + jsw * 8;
    bf16_t* dstp = &sAB[isB * 8192 + ci0 * 512 + lane * 8];
    const size_t srcChunkStride = (size_t)8 * K;

    const int wm = wave >> 1;
    const int wn = wave & 1;
    const int la = lane & 15;
    const int jA = lane >> 4;
    const int jj0 = (jA ^ (lane & 7)) * 8;
    const int aoff = (wm * 64 + la) * 64 + jj0;
    const int boff = 8192 + (wn * 64 + la) * 64 + jj0;

    f32x4 acc[4][4] = {};
    for (int kt = 0; kt < K; kt += 64) {
#pragma unroll
        for (int j8 = 0; j8 < 8; ++j8)
            __builtin_amdgcn_global_load_lds((gptr_t)(srcp + j8 * srcChunkStride),
                                             (lptr_t)(dstp + j8 * 512), 16, 0, 0);
        srcp += 64;
        __syncthreads();
#pragma unroll
        for (int kh = 0; kh < 2; ++kh) {
            const int kx = kh * 32;
            bf16x8 a[4], b[4];
#pragma unroll
            for (int i = 0; i < 4; ++i) a[i] = *(const bf16x8*)&sAB[(aoff + i * 1024) ^ kx];
#pragma unroll
            for (int i = 0; i < 4; ++i) b[i] = *(const bf16x8*)&sAB[(boff + i * 1024) ^ kx];
#pragma unroll
            for (int mi = 0; mi < 4; ++mi)
#pragma unroll
                for (int ni = 0; ni < 4; ++ni)
                    acc[mi][ni] = __builtin_amdgcn_mfma_f32_16x16x32_bf16(
                        a[mi], b[ni], acc[mi][ni], 0, 0, 0);
        }
        __syncthreads();
    }
    const int col0 = tileN + wn * 64 + la;
    const int row0 = tileM + wm * 64 + jA * 4;
    float bv[4];
#pragma unroll
    for (int ni = 0; ni < 4; ++ni) bv[ni] = bias[col0 + ni * 16];
#pragma unroll
    for (int mi = 0; mi < 4; ++mi)
#pragma unroll
        for (int ni = 0; ni < 4; ++ni)
#pragma unroll
            for (int r = 0; r < 4; ++r)
                C[(size_t)(row0 + mi * 16 + r) * N + (col0 + ni * 16)] =
                    acc[mi][ni][r] + bv[ni];
}

extern "C" void kernel_launch(void* const* d_in, const int* in_sizes, int n_in,
                              void* d_out, int out_size, void* d_ws, size_t ws_size,
                              hipStream_t stream) {
    const float* x        = (const float*)d_in[0];
    const int*   w_codes  = (const int*)d_in[1];
    const float* w_absmax = (const float*)d_in[2];
    const int*   b_codes  = (const int*)d_in[3];
    const float* b_absmax = (const float*)d_in[4];
    float* out = (float*)d_out;

    const int  D_OUT = in_sizes[3];
    const long WK    = (long)in_sizes[1];
    const int  D_IN  = (int)(WK / D_OUT);
    const long xN    = (long)in_sizes[0];
    const int  M     = (int)(xN / D_IN);
    const int  N = D_OUT, K = D_IN;

    unsigned short* wsW = (unsigned short*)d_ws;
    unsigned short* wsA = wsW + (size_t)N * K;
    float* wsBias = (float*)(wsA + (size_t)M * K);

    long w16 = WK / 16;
    long x16 = xN / 16;
    long wb = (w16 + 255) / 256;
    long xb = (x16 + 255) / 256;
    long bb = (D_OUT + 255) / 256;
    prep_kernel<<<dim3((unsigned)(wb + xb + bb)), dim3(256), 0, stream>>>(
        w_codes, w_absmax, x, b_codes, b_absmax, wsW, wsA, wsBias,
        w16, x16, D_OUT, wb, xb);

    if (M % 256 == 0) {
        gemm_bias_kernel_256<<<dim3(N / 128, M / 256), dim3(512), 0, stream>>>(
            (const bf16_t*)wsA, (const bf16_t*)wsW, wsBias, out, M, N, K);
    } else {
        gemm_bias_kernel_128<<<dim3(N / 128, M / 128), dim3(256), 0, stream>>>(
            (const bf16_t*)wsA, (const bf16_t*)wsW, wsBias, out, M, N, K);
    }
}